// Round 6
// baseline (308.361 us; speedup 1.0000x reference)
//
#include <hip/hip_runtime.h>
#include <hip/hip_bf16.h>

#define NN 32768
#define EE 524288
#define GG 256
#define PP 128
// padded CSR capacity: every node rounded up to multiple of 4 edges
#define CSR_CAP4 155652   // int4 units; >= (EE + 3*NN)/4

// ---------------------------------------------------------------------------
// k_init: blocks 0..8191 -> h = normalize(relu(x @ W1.T + b1)), wave/node.
//         blocks < 128 also zero deg[].
//         blocks 8192..8223 -> fold W2/W3/W4/biases into Wc[kk][o] + c.
//         block 8224 -> transpose Wd1 -> Wd1t.
//         block 8225 -> zero sentinel row NN of h0 and h1 (gather pad target).
// ---------------------------------------------------------------------------
__global__ void k_init(const float* __restrict__ x, const float* __restrict__ W1,
                       const float* __restrict__ b1,
                       const float* __restrict__ W2, const float* __restrict__ b2,
                       const float* __restrict__ W3, const float* __restrict__ b3,
                       const float* __restrict__ W4, const float* __restrict__ b4,
                       const float* __restrict__ Wd1,
                       float* __restrict__ h0, float* __restrict__ h1,
                       float* __restrict__ Wc, float* __restrict__ Wd1t,
                       int* __restrict__ deg) {
    __shared__ float tile[128 * 65];
    int b = blockIdx.x, t = threadIdx.x;
    if (b >= 8192) {
        if (b == 8224) {                       // Wd1 transpose
            for (int idx = t; idx < 8192; idx += 256) {
                int q = idx >> 6, o = idx & 63;
                tile[q*65 + o] = Wd1[idx];
            }
            __syncthreads();
            for (int idx = t; idx < 8192; idx += 256) {
                int o = idx >> 7, q = idx & 127;
                Wd1t[idx] = tile[q*65 + o];
            }
        } else if (b == 8225) {                // zero sentinel rows
            if (t < 64)       h0[(long)NN*64 + t] = 0.f;
            else if (t < 128) h1[(long)NN*64 + (t-64)] = 0.f;
        } else {                               // Wc fold
            int idx = (b - 8192) * 256 + t;    // 0..8191
            int kk = idx >> 6, o = idx & 63;
            float a = 0.f;
            if (kk < 64) {
                for (int j = 0; j < 64; ++j) a += W4[o*128 + j] * W3[j*64 + kk];
            } else {
                int k2 = kk - 64;
                for (int j = 0; j < 64; ++j) a += W4[o*128 + 64 + j] * W2[j*64 + k2];
            }
            Wc[kk*64 + o] = a;
            if (idx < 64) {
                float c = b4[idx];
                for (int j = 0; j < 64; ++j)
                    c += W4[idx*128 + j]*b3[j] + W4[idx*128 + 64 + j]*b2[j];
                Wc[8192 + idx] = c;
            }
        }
        return;
    }
    if (b < 128) deg[b * 256 + t] = 0;
    int node = (b * 256 + t) >> 6;
    int lane = t & 63;
    float acc = b1[lane];
    #pragma unroll
    for (int j = 0; j < 8; ++j)
        acc += x[node*8 + j] * W1[lane*8 + j];
    acc = fmaxf(acc, 0.f);
    float ss = acc * acc;
    #pragma unroll
    for (int m = 1; m < 64; m <<= 1) ss += __shfl_xor(ss, m, 64);
    h0[node*64 + lane] = acc / sqrtf(ss);
}

// ---------------------------------------------------------------------------
// k_hist: int4 degree histogram + csr sentinel prefill (pad slots -> NN).
// ---------------------------------------------------------------------------
__global__ void k_hist(const int* __restrict__ dst, int* __restrict__ deg,
                       int* __restrict__ csr) {
    int i = blockIdx.x * blockDim.x + threadIdx.x;   // 131072 threads
    int4 d = ((const int4*)dst)[i];
    atomicAdd(&deg[d.x], 1);
    atomicAdd(&deg[d.y], 1);
    atomicAdd(&deg[d.z], 1);
    atomicAdd(&deg[d.w], 1);
    int4 s = make_int4(NN, NN, NN, NN);
    for (int j = i; j < CSR_CAP4; j += 131072)
        ((int4*)csr)[j] = s;
}

// ---------------------------------------------------------------------------
// k_scan: 1024-thread register scan over PADDED degrees ((d+3)&~3).
// Emits offs (all multiples of 4), cur copy, and offs[NN] sentinel.
// ---------------------------------------------------------------------------
__global__ void __launch_bounds__(1024) k_scan(
        const int* __restrict__ deg, int* __restrict__ offs,
        int* __restrict__ cur) {
    __shared__ int part[1024];
    int t = threadIdx.x;
    int4 v[8];
    int base4 = t * 8;                  // 32 ints per thread
    int s = 0;
    #pragma unroll
    for (int j = 0; j < 8; ++j) {
        v[j] = ((const int4*)deg)[base4 + j];
        s += ((v[j].x+3)&~3) + ((v[j].y+3)&~3) + ((v[j].z+3)&~3) + ((v[j].w+3)&~3);
    }
    part[t] = s;
    __syncthreads();
    for (int off = 1; off < 1024; off <<= 1) {
        int tmp = (t >= off) ? part[t - off] : 0;
        __syncthreads();
        part[t] += tmp;
        __syncthreads();
    }
    int run = part[t] - s;
    #pragma unroll
    for (int j = 0; j < 8; ++j) {
        int4 o;
        o.x = run; run += (v[j].x+3)&~3;
        o.y = run; run += (v[j].y+3)&~3;
        o.z = run; run += (v[j].z+3)&~3;
        o.w = run; run += (v[j].w+3)&~3;
        ((int4*)offs)[base4 + j] = o;
        ((int4*)cur)[base4 + j]  = o;
    }
    if (t == 1023) offs[NN] = part[1023];   // padded total
}

__global__ void k_fill(const int* __restrict__ src, const int* __restrict__ dst,
                       int* __restrict__ cur, int* __restrict__ csr) {
    int i = blockIdx.x * blockDim.x + threadIdx.x;   // 131072 threads
    int4 s4 = ((const int4*)src)[i];
    int4 d4 = ((const int4*)dst)[i];
    csr[atomicAdd(&cur[d4.x], 1)] = s4.x;
    csr[atomicAdd(&cur[d4.y], 1)] = s4.y;
    csr[atomicAdd(&cur[d4.z], 1)] = s4.z;
    csr[atomicAdd(&cur[d4.w], 1)] = s4.w;
}

// ---------------------------------------------------------------------------
// k_gather: segment_sum via padded CSR. ONE NODE PER WAVE, no LDS/barriers.
// Lane split: fg4=(lane&15)*4 features (float4), es=lane>>4 int4-slot.
// Segments are multiples of 4 edges; pad entries are node NN whose h-row is
// zero, so the round is branchless: 1 aligned int4 index load (broadcast
// within 16-lane group) + 4 float4 row gathers + pure adds.
// Cross-slot reduce: shfl_xor 16/32; es==0 writes the 256 B row.
// ---------------------------------------------------------------------------
__global__ void __launch_bounds__(256) k_gather(
        const float* __restrict__ h, const int* __restrict__ offs,
        const int* __restrict__ csr, float* __restrict__ m) {
    int node = (blockIdx.x * blockDim.x + threadIdx.x) >> 6;
    int lane = threadIdx.x & 63;
    int fg4 = (lane & 15) * 4, es = lane >> 4;
    int st = offs[node];
    int de4 = (offs[node + 1] - st) >> 2;       // int4 units
    int st4 = st >> 2;
    const int4* csr4 = (const int4*)csr;
    float4 acc = make_float4(0.f, 0.f, 0.f, 0.f);
    for (int q = es; q < de4; q += 4) {
        int4 idx = csr4[st4 + q];
        float4 v0 = *(const float4*)&h[(long)idx.x*64 + fg4];
        float4 v1 = *(const float4*)&h[(long)idx.y*64 + fg4];
        float4 v2 = *(const float4*)&h[(long)idx.z*64 + fg4];
        float4 v3 = *(const float4*)&h[(long)idx.w*64 + fg4];
        acc.x += (v0.x + v1.x) + (v2.x + v3.x);
        acc.y += (v0.y + v1.y) + (v2.y + v3.y);
        acc.z += (v0.z + v1.z) + (v2.z + v3.z);
        acc.w += (v0.w + v1.w) + (v2.w + v3.w);
    }
    acc.x += __shfl_xor(acc.x, 16, 64); acc.y += __shfl_xor(acc.y, 16, 64);
    acc.z += __shfl_xor(acc.z, 16, 64); acc.w += __shfl_xor(acc.w, 16, 64);
    acc.x += __shfl_xor(acc.x, 32, 64); acc.y += __shfl_xor(acc.y, 32, 64);
    acc.z += __shfl_xor(acc.z, 32, 64); acc.w += __shfl_xor(acc.w, 32, 64);
    if (es == 0) *(float4*)&m[(long)node*64 + fg4] = acc;
}

// ---------------------------------------------------------------------------
// k_gemm: hn[n][o] = normalize(relu(sum_kk X[n][kk]*Wc[kk][o] + c[o])),
// X = [m | h]. 64-node tile (512 blocks = 2/CU), thread tile 4n x 4o:
// 0.5 LDS-floats/MAC (vs 0.75 at 2n) and half the Wc restaging.
// mio holds m on entry and receives hn (block-local alias: tile staged to
// LDS before overwrite; sentinel row NN untouched).
// ---------------------------------------------------------------------------
__global__ void __launch_bounds__(256) k_gemm(
        const float* __restrict__ Wc, float* mio,
        const float* __restrict__ hcur) {
    __shared__ float Wl[8192];       // [kk][o], stride 64
    __shared__ float Xl[64 * 132];   // [n][kk], stride 132
    int t = threadIdx.x;
    int nbase = blockIdx.x * 64;

    for (int i = t * 4; i < 8192; i += 1024)
        *(float4*)&Wl[i] = *(const float4*)&Wc[i];
    for (int idx = t; idx < 1024; idx += 256) {
        int n = idx >> 4, c = (idx & 15) * 4;
        *(float4*)&Xl[n*132 + c]      = *(const float4*)&mio[(long)(nbase+n)*64 + c];
        *(float4*)&Xl[n*132 + 64 + c] = *(const float4*)&hcur[(long)(nbase+n)*64 + c];
    }
    __syncthreads();

    int tc = t & 15, tr = t >> 4;
    int o0 = tc * 4, n0 = tr * 4;
    float4 c4 = *(const float4*)&Wc[8192 + o0];
    float acc[4][4] = {};
    #pragma unroll 2
    for (int kk = 0; kk < 128; kk += 4) {
        float4 w0 = *(float4*)&Wl[(kk+0)*64 + o0];
        float4 w1 = *(float4*)&Wl[(kk+1)*64 + o0];
        float4 w2 = *(float4*)&Wl[(kk+2)*64 + o0];
        float4 w3 = *(float4*)&Wl[(kk+3)*64 + o0];
        #pragma unroll
        for (int jn = 0; jn < 4; ++jn) {
            float4 xv = *(float4*)&Xl[(n0+jn)*132 + kk];
            acc[jn][0] += xv.x*w0.x + xv.y*w1.x + xv.z*w2.x + xv.w*w3.x;
            acc[jn][1] += xv.x*w0.y + xv.y*w1.y + xv.z*w2.y + xv.w*w3.y;
            acc[jn][2] += xv.x*w0.z + xv.y*w1.z + xv.z*w2.z + xv.w*w3.z;
            acc[jn][3] += xv.x*w0.w + xv.y*w1.w + xv.z*w2.w + xv.w*w3.w;
        }
    }

    #pragma unroll
    for (int jn = 0; jn < 4; ++jn) {
        float v0 = fmaxf(acc[jn][0] + c4.x, 0.f);
        float v1 = fmaxf(acc[jn][1] + c4.y, 0.f);
        float v2 = fmaxf(acc[jn][2] + c4.z, 0.f);
        float v3 = fmaxf(acc[jn][3] + c4.w, 0.f);
        float ss = v0*v0 + v1*v1 + v2*v2 + v3*v3;
        ss += __shfl_xor(ss, 1, 64);
        ss += __shfl_xor(ss, 2, 64);
        ss += __shfl_xor(ss, 4, 64);
        ss += __shfl_xor(ss, 8, 64);
        float r = 1.0f / sqrtf(ss);
        float4 outv = make_float4(v0*r, v1*r, v2*r, v3*r);
        *(float4*)&mio[(long)(nbase + n0 + jn)*64 + o0] = outv;
    }
}

// ---------------------------------------------------------------------------
// k_tmat: Tt[g][i*64+o] = sum_j W5[o][i*64+j] * last[g][j].
// 256 blocks = 16 consecutive rows r = i*64+o each; thread = graph.
// ---------------------------------------------------------------------------
__global__ void __launch_bounds__(256) k_tmat(
        const float* __restrict__ h, const float* __restrict__ W5,
        float* __restrict__ Tt) {
    __shared__ float lastL[256 * 65];   // 66.6 KB
    __shared__ float wL[64 * 16];       // [j][rr]
    __shared__ float tr[16 * 257];      // [rr][g]
    int t = threadIdx.x;
    int rb = blockIdx.x * 16;
    int i = rb >> 6, obase = rb & 63;

    for (int idx4 = t; idx4 < 4096; idx4 += 256) {
        int g = idx4 >> 4, c = (idx4 & 15) * 4;
        *(float4*)&lastL[g*65 + c] =
            *(const float4*)&h[((long)g*128 + 127)*64 + c];
    }
    {   // stage W5 slice, transposed to [j][rr]
        int rr = t & 15, j0 = (t >> 4) * 4;
        float4 w = *(const float4*)&W5[(long)(obase + rr)*4096 + i*64 + j0];
        wL[(j0+0)*16 + rr] = w.x;
        wL[(j0+1)*16 + rr] = w.y;
        wL[(j0+2)*16 + rr] = w.z;
        wL[(j0+3)*16 + rr] = w.w;
    }
    __syncthreads();

    int g = t;
    float acc[16] = {};
    for (int j = 0; j < 64; ++j) {
        float lv = lastL[g*65 + j];
        #pragma unroll
        for (int r4 = 0; r4 < 4; ++r4) {
            float4 wv = *(float4*)&wL[j*16 + r4*4];
            acc[r4*4+0] += wv.x * lv;
            acc[r4*4+1] += wv.y * lv;
            acc[r4*4+2] += wv.z * lv;
            acc[r4*4+3] += wv.w * lv;
        }
    }
    #pragma unroll
    for (int rr = 0; rr < 16; ++rr) tr[rr*257 + g] = acc[rr];
    __syncthreads();
    for (int it = 0; it < 4; ++it) {
        int idx = t + it*256;
        int g2 = idx >> 2, c4 = idx & 3;
        float4 v = make_float4(tr[(c4*4+0)*257 + g2], tr[(c4*4+1)*257 + g2],
                               tr[(c4*4+2)*257 + g2], tr[(c4*4+3)*257 + g2]);
        *(float4*)&Tt[(long)g2*4096 + rb + c4*4] = v;
    }
}

// ---------------------------------------------------------------------------
// k_readout: per-graph GEMM chain, 2 blocks/graph, 2 p-tiles of 32 each.
// ---------------------------------------------------------------------------
__global__ void __launch_bounds__(256) k_readout(
        const float* __restrict__ h, const float* __restrict__ Tt,
        const float* __restrict__ b5, const float* __restrict__ Wd1t,
        const float* __restrict__ bd1, const float* __restrict__ Wd2,
        const float* __restrict__ bd2, float* __restrict__ out) {
    __shared__ float Tl[4096];       // [i][o], stride 64
    __shared__ float W1t[8192];      // [o][q], stride 128
    __shared__ float OY[32 * 68];    // [p][i] then [p][o], stride 68
    int t = threadIdx.x;
    int g = blockIdx.x >> 1, half = blockIdx.x & 1;

    for (int i = t * 4; i < 4096; i += 1024)
        *(float4*)&Tl[i] = *(const float4*)&Tt[(long)g*4096 + i];
    for (int i = t * 4; i < 8192; i += 1024)
        *(float4*)&W1t[i] = *(const float4*)&Wd1t[i];

    int tc = t & 15, tr = t >> 4;      // GEMM1 map
    int o0 = tc * 4, p0 = tr * 2;
    int tc2 = t & 31, tr2 = t >> 5;    // GEMM2 map
    int q0 = tc2 * 4, pp0 = tr2 * 4;
    float4 b5_4  = *(const float4*)&b5[o0];
    float4 bd1_4 = *(const float4*)&bd1[q0];
    float4 wd2_4 = *(const float4*)&Wd2[q0];
    float bd2v = bd2[0];

    for (int pt = half*2; pt < half*2 + 2; ++pt) {
        int pbase = pt * 32;
        __syncthreads();
        for (int idx = t; idx < 512; idx += 256) {
            int p = idx >> 4, c = (idx & 15) * 4;
            *(float4*)&OY[p*68 + c] =
                *(const float4*)&h[((long)g*128 + pbase + p)*64 + c];
        }
        __syncthreads();

        // GEMM1
        float a10[4] = {0.f,0.f,0.f,0.f};
        float a11[4] = {0.f,0.f,0.f,0.f};
        #pragma unroll 4
        for (int i = 0; i < 64; i += 4) {
            float4 w0 = *(float4*)&Tl[(i+0)*64 + o0];
            float4 w1 = *(float4*)&Tl[(i+1)*64 + o0];
            float4 w2 = *(float4*)&Tl[(i+2)*64 + o0];
            float4 w3 = *(float4*)&Tl[(i+3)*64 + o0];
            float4 x0 = *(float4*)&OY[(p0+0)*68 + i];
            float4 x1 = *(float4*)&OY[(p0+1)*68 + i];
            a10[0] += x0.x*w0.x + x0.y*w1.x + x0.z*w2.x + x0.w*w3.x;
            a10[1] += x0.x*w0.y + x0.y*w1.y + x0.z*w2.y + x0.w*w3.y;
            a10[2] += x0.x*w0.z + x0.y*w1.z + x0.z*w2.z + x0.w*w3.z;
            a10[3] += x0.x*w0.w + x0.y*w1.w + x0.z*w2.w + x0.w*w3.w;
            a11[0] += x1.x*w0.x + x1.y*w1.x + x1.z*w2.x + x1.w*w3.x;
            a11[1] += x1.x*w0.y + x1.y*w1.y + x1.z*w2.y + x1.w*w3.y;
            a11[2] += x1.x*w0.z + x1.y*w1.z + x1.z*w2.z + x1.w*w3.z;
            a11[3] += x1.x*w0.w + x1.y*w1.w + x1.z*w2.w + x1.w*w3.w;
        }
        __syncthreads();

        float4 y0 = make_float4(a10[0]+b5_4.x, a10[1]+b5_4.y, a10[2]+b5_4.z, a10[3]+b5_4.w);
        float4 y1 = make_float4(a11[0]+b5_4.x, a11[1]+b5_4.y, a11[2]+b5_4.z, a11[3]+b5_4.w);
        *(float4*)&OY[(p0+0)*68 + o0] = y0;
        *(float4*)&OY[(p0+1)*68 + o0] = y1;
        __syncthreads();

        // GEMM2
        float a2[4][4] = {};
        #pragma unroll 4
        for (int o = 0; o < 64; o += 4) {
            float4 w0 = *(float4*)&W1t[(o+0)*128 + q0];
            float4 w1 = *(float4*)&W1t[(o+1)*128 + q0];
            float4 w2 = *(float4*)&W1t[(o+2)*128 + q0];
            float4 w3 = *(float4*)&W1t[(o+3)*128 + q0];
            #pragma unroll
            for (int jp = 0; jp < 4; ++jp) {
                float4 yv = *(float4*)&OY[(pp0+jp)*68 + o];
                a2[jp][0] += yv.x*w0.x + yv.y*w1.x + yv.z*w2.x + yv.w*w3.x;
                a2[jp][1] += yv.x*w0.y + yv.y*w1.y + yv.z*w2.y + yv.w*w3.y;
                a2[jp][2] += yv.x*w0.z + yv.y*w1.z + yv.z*w2.z + yv.w*w3.z;
                a2[jp][3] += yv.x*w0.w + yv.y*w1.w + yv.z*w2.w + yv.w*w3.w;
            }
        }

        #pragma unroll
        for (int jp = 0; jp < 4; ++jp) {
            float s = wd2_4.x * fmaxf(a2[jp][0] + bd1_4.x, 0.f)
                    + wd2_4.y * fmaxf(a2[jp][1] + bd1_4.y, 0.f)
                    + wd2_4.z * fmaxf(a2[jp][2] + bd1_4.z, 0.f)
                    + wd2_4.w * fmaxf(a2[jp][3] + bd1_4.w, 0.f);
            s += __shfl_xor(s, 1, 64);
            s += __shfl_xor(s, 2, 64);
            s += __shfl_xor(s, 4, 64);
            s += __shfl_xor(s, 8, 64);
            s += __shfl_xor(s, 16, 64);
            if (tc2 == 0) {
                int p = pbase + pp0 + jp;
                if (p < 127) out[g*127 + p] = s + bd2v;
            }
        }
    }
}

extern "C" void kernel_launch(void* const* d_in, const int* in_sizes, int n_in,
                              void* d_out, int out_size, void* d_ws, size_t ws_size,
                              hipStream_t stream) {
    const float* x   = (const float*)d_in[0];
    const int*   ei  = (const int*)d_in[1];   // [2][E] int32
    const float* W1  = (const float*)d_in[4];
    const float* b1  = (const float*)d_in[5];
    const float* W2  = (const float*)d_in[6];
    const float* b2  = (const float*)d_in[7];
    const float* W3  = (const float*)d_in[8];
    const float* b3  = (const float*)d_in[9];
    const float* W4  = (const float*)d_in[10];
    const float* b4  = (const float*)d_in[11];
    const float* W5  = (const float*)d_in[12];
    const float* b5  = (const float*)d_in[13];
    const float* Wd1 = (const float*)d_in[14];
    const float* bd1 = (const float*)d_in[15];
    const float* Wd2 = (const float*)d_in[16];
    const float* bd2 = (const float*)d_in[17];
    float* out = (float*)d_out;

    float* ws  = (float*)d_ws;
    float* h0   = ws;                        // (NN+1)*64 floats (row NN = zeros)
    float* h1   = ws + 2129984;              // (NN+1)*64 floats, 16-aligned
    float* Tt   = ws + 4259968;              // 2^20 floats
    float* Wc   = ws + 5308416;              // 8448 floats
    float* Wd1t = ws + 5316864;              // 8192 floats
    int*   deg  = (int*)(ws + 5325056);      // NN
    int*   offs = deg + NN;                  // NN+1 (+pad)
    int*   cur  = offs + NN + 16;            // NN
    int*   csr  = cur + NN;                  // CSR_CAP4*4 ints (padded)

    const int* src = ei;
    const int* dst = ei + EE;

    k_init<<<8226, 256, 0, stream>>>(x, W1, b1, W2, b2, W3, b3, W4, b4,
                                     Wd1, h0, h1, Wc, Wd1t, deg);
    k_hist<<<512, 256, 0, stream>>>(dst, deg, csr);
    k_scan<<<1, 1024, 0, stream>>>(deg, offs, cur);
    k_fill<<<512, 256, 0, stream>>>(src, dst, cur, csr);

    float* hc = h0; float* hn = h1;
    for (int l = 0; l < 3; ++l) {
        // gather writes messages into hn rows 0..NN-1; k_gemm consumes them
        // in-place and overwrites hn with updated features (block-local
        // alias). Sentinel row NN of both buffers stays zero throughout.
        k_gather<<<NN/4, 256, 0, stream>>>(hc, offs, csr, hn);
        k_gemm<<<NN/64, 256, 0, stream>>>(Wc, hn, hc);
        float* tmp = hc; hc = hn; hn = tmp;
    }

    k_tmat<<<256, 256, 0, stream>>>(hc, W5, Tt);
    k_readout<<<512, 256, 0, stream>>>(hc, Tt, b5, Wd1t, bd1, Wd2, bd2, out);
}

// Round 7
// 271.306 us; speedup vs baseline: 1.1366x; 1.1366x over previous
//
#include <hip/hip_runtime.h>
#include <hip/hip_bf16.h>

#define NN 32768
#define EE 524288
#define GG 256
#define PP 128
// fixed-capacity CSR bucket: 64 slots/node (P(deg>64) ~ 1e-55 for Poisson(16))

// ---------------------------------------------------------------------------
// k_init: blocks 0..8191 -> h = normalize(relu(x @ W1.T + b1)), wave/node;
//         these blocks also prefill csr bucket with sentinel NN (64 int4 each)
//         and blocks < 128 zero deg[].
//         blocks 8192..8223 -> fold W2/W3/W4/biases into Wc[kk][o] + c.
//         block 8224 -> transpose Wd1 -> Wd1t.
//         block 8225 -> zero sentinel row NN of h0 and h1 (gather pad target).
// ---------------------------------------------------------------------------
__global__ void k_init(const float* __restrict__ x, const float* __restrict__ W1,
                       const float* __restrict__ b1,
                       const float* __restrict__ W2, const float* __restrict__ b2,
                       const float* __restrict__ W3, const float* __restrict__ b3,
                       const float* __restrict__ W4, const float* __restrict__ b4,
                       const float* __restrict__ Wd1,
                       float* __restrict__ h0, float* __restrict__ h1,
                       float* __restrict__ Wc, float* __restrict__ Wd1t,
                       int* __restrict__ deg, int* __restrict__ csr) {
    __shared__ float tile[128 * 65];
    int b = blockIdx.x, t = threadIdx.x;
    if (b >= 8192) {
        if (b == 8224) {                       // Wd1 transpose
            for (int idx = t; idx < 8192; idx += 256) {
                int q = idx >> 6, o = idx & 63;
                tile[q*65 + o] = Wd1[idx];
            }
            __syncthreads();
            for (int idx = t; idx < 8192; idx += 256) {
                int o = idx >> 7, q = idx & 127;
                Wd1t[idx] = tile[q*65 + o];
            }
        } else if (b == 8225) {                // zero sentinel rows
            if (t < 64)       h0[(long)NN*64 + t] = 0.f;
            else if (t < 128) h1[(long)NN*64 + (t-64)] = 0.f;
        } else {                               // Wc fold
            int idx = (b - 8192) * 256 + t;    // 0..8191
            int kk = idx >> 6, o = idx & 63;
            float a = 0.f;
            if (kk < 64) {
                for (int j = 0; j < 64; ++j) a += W4[o*128 + j] * W3[j*64 + kk];
            } else {
                int k2 = kk - 64;
                for (int j = 0; j < 64; ++j) a += W4[o*128 + 64 + j] * W2[j*64 + k2];
            }
            Wc[kk*64 + o] = a;
            if (idx < 64) {
                float c = b4[idx];
                for (int j = 0; j < 64; ++j)
                    c += W4[idx*128 + j]*b3[j] + W4[idx*128 + 64 + j]*b2[j];
                Wc[8192 + idx] = c;
            }
        }
        return;
    }
    if (b < 128) deg[b * 256 + t] = 0;
    if (t < 64)  // csr bucket sentinel prefill: 64 int4 per block x 8192 blocks
        ((int4*)csr)[b*64 + t] = make_int4(NN, NN, NN, NN);
    int node = (b * 256 + t) >> 6;
    int lane = t & 63;
    float acc = b1[lane];
    #pragma unroll
    for (int j = 0; j < 8; ++j)
        acc += x[node*8 + j] * W1[lane*8 + j];
    acc = fmaxf(acc, 0.f);
    float ss = acc * acc;
    #pragma unroll
    for (int m = 1; m < 64; m <<= 1) ss += __shfl_xor(ss, m, 64);
    h0[node*64 + lane] = acc / sqrtf(ss);
}

// ---------------------------------------------------------------------------
// k_fill: direct bucket CSR build (replaces hist+scan+fill).
// csr[dst*64 + pos] = src; deg[dst] counts. Slot order nondeterministic
// (harmless: segment-sum order was already nondeterministic).
// ---------------------------------------------------------------------------
__global__ void k_fill(const int* __restrict__ src, const int* __restrict__ dst,
                       int* __restrict__ deg, int* __restrict__ csr) {
    int i = blockIdx.x * blockDim.x + threadIdx.x;   // 131072 threads
    int4 s4 = ((const int4*)src)[i];
    int4 d4 = ((const int4*)dst)[i];
    csr[(d4.x << 6) + atomicAdd(&deg[d4.x], 1)] = s4.x;
    csr[(d4.y << 6) + atomicAdd(&deg[d4.y], 1)] = s4.y;
    csr[(d4.z << 6) + atomicAdd(&deg[d4.z], 1)] = s4.z;
    csr[(d4.w << 6) + atomicAdd(&deg[d4.w], 1)] = s4.w;
}

// ---------------------------------------------------------------------------
// k_gather: segment_sum via bucket CSR. ONE NODE PER WAVE, no LDS/barriers.
// Lane split: fg4=(lane&15)*4 features (float4), es=lane>>4 int4-slot.
// Pad slots hold sentinel NN whose h-row is zero -> branchless rounds:
// 1 aligned int4 index load + 4 float4 row gathers + adds.
// Cross-slot reduce: shfl_xor 16/32; es==0 writes the 256 B row.
// ---------------------------------------------------------------------------
__global__ void __launch_bounds__(256) k_gather(
        const float* __restrict__ h, const int* __restrict__ deg,
        const int* __restrict__ csr, float* __restrict__ m) {
    int node = (blockIdx.x * blockDim.x + threadIdx.x) >> 6;
    int lane = threadIdx.x & 63;
    int fg4 = (lane & 15) * 4, es = lane >> 4;
    int dg = __builtin_amdgcn_readfirstlane(deg[node]);
    int de4 = (dg + 3) >> 2;                    // int4 rounds
    const int4* csr4 = (const int4*)csr + node * 16;
    float4 acc = make_float4(0.f, 0.f, 0.f, 0.f);
    for (int q = es; q < de4; q += 4) {
        int4 idx = csr4[q];
        float4 v0 = *(const float4*)&h[(long)idx.x*64 + fg4];
        float4 v1 = *(const float4*)&h[(long)idx.y*64 + fg4];
        float4 v2 = *(const float4*)&h[(long)idx.z*64 + fg4];
        float4 v3 = *(const float4*)&h[(long)idx.w*64 + fg4];
        acc.x += (v0.x + v1.x) + (v2.x + v3.x);
        acc.y += (v0.y + v1.y) + (v2.y + v3.y);
        acc.z += (v0.z + v1.z) + (v2.z + v3.z);
        acc.w += (v0.w + v1.w) + (v2.w + v3.w);
    }
    acc.x += __shfl_xor(acc.x, 16, 64); acc.y += __shfl_xor(acc.y, 16, 64);
    acc.z += __shfl_xor(acc.z, 16, 64); acc.w += __shfl_xor(acc.w, 16, 64);
    acc.x += __shfl_xor(acc.x, 32, 64); acc.y += __shfl_xor(acc.y, 32, 64);
    acc.z += __shfl_xor(acc.z, 32, 64); acc.w += __shfl_xor(acc.w, 32, 64);
    if (es == 0) *(float4*)&m[(long)node*64 + fg4] = acc;
}

// ---------------------------------------------------------------------------
// k_gemm: hn[n][o] = normalize(relu(sum_kk X[n][kk]*Wc[kk][o] + c[o])),
// X = [m | h]. 64-node tile (512 blocks = 2/CU), thread tile 4n x 4o.
// mio holds m on entry and receives hn (block-local alias: tile staged to
// LDS before overwrite; sentinel row NN untouched).
// ---------------------------------------------------------------------------
__global__ void __launch_bounds__(256) k_gemm(
        const float* __restrict__ Wc, float* mio,
        const float* __restrict__ hcur) {
    __shared__ float Wl[8192];       // [kk][o], stride 64
    __shared__ float Xl[64 * 132];   // [n][kk], stride 132
    int t = threadIdx.x;
    int nbase = blockIdx.x * 64;

    for (int i = t * 4; i < 8192; i += 1024)
        *(float4*)&Wl[i] = *(const float4*)&Wc[i];
    for (int idx = t; idx < 1024; idx += 256) {
        int n = idx >> 4, c = (idx & 15) * 4;
        *(float4*)&Xl[n*132 + c]      = *(const float4*)&mio[(long)(nbase+n)*64 + c];
        *(float4*)&Xl[n*132 + 64 + c] = *(const float4*)&hcur[(long)(nbase+n)*64 + c];
    }
    __syncthreads();

    int tc = t & 15, tr = t >> 4;
    int o0 = tc * 4, n0 = tr * 4;
    float4 c4 = *(const float4*)&Wc[8192 + o0];
    float acc[4][4] = {};
    #pragma unroll 2
    for (int kk = 0; kk < 128; kk += 4) {
        float4 w0 = *(float4*)&Wl[(kk+0)*64 + o0];
        float4 w1 = *(float4*)&Wl[(kk+1)*64 + o0];
        float4 w2 = *(float4*)&Wl[(kk+2)*64 + o0];
        float4 w3 = *(float4*)&Wl[(kk+3)*64 + o0];
        #pragma unroll
        for (int jn = 0; jn < 4; ++jn) {
            float4 xv = *(float4*)&Xl[(n0+jn)*132 + kk];
            acc[jn][0] += xv.x*w0.x + xv.y*w1.x + xv.z*w2.x + xv.w*w3.x;
            acc[jn][1] += xv.x*w0.y + xv.y*w1.y + xv.z*w2.y + xv.w*w3.y;
            acc[jn][2] += xv.x*w0.z + xv.y*w1.z + xv.z*w2.z + xv.w*w3.z;
            acc[jn][3] += xv.x*w0.w + xv.y*w1.w + xv.z*w2.w + xv.w*w3.w;
        }
    }

    #pragma unroll
    for (int jn = 0; jn < 4; ++jn) {
        float v0 = fmaxf(acc[jn][0] + c4.x, 0.f);
        float v1 = fmaxf(acc[jn][1] + c4.y, 0.f);
        float v2 = fmaxf(acc[jn][2] + c4.z, 0.f);
        float v3 = fmaxf(acc[jn][3] + c4.w, 0.f);
        float ss = v0*v0 + v1*v1 + v2*v2 + v3*v3;
        ss += __shfl_xor(ss, 1, 64);
        ss += __shfl_xor(ss, 2, 64);
        ss += __shfl_xor(ss, 4, 64);
        ss += __shfl_xor(ss, 8, 64);
        float r = 1.0f / sqrtf(ss);
        float4 outv = make_float4(v0*r, v1*r, v2*r, v3*r);
        *(float4*)&mio[(long)(nbase + n0 + jn)*64 + o0] = outv;
    }
}

// ---------------------------------------------------------------------------
// k_tmat: Tt[g][i*64+o] = sum_j W5[o][i*64+j] * last[g][j].
// 256 blocks = 16 consecutive rows r = i*64+o each; thread = graph.
// ---------------------------------------------------------------------------
__global__ void __launch_bounds__(256) k_tmat(
        const float* __restrict__ h, const float* __restrict__ W5,
        float* __restrict__ Tt) {
    __shared__ float lastL[256 * 65];   // 66.6 KB
    __shared__ float wL[64 * 16];       // [j][rr]
    __shared__ float tr[16 * 257];      // [rr][g]
    int t = threadIdx.x;
    int rb = blockIdx.x * 16;
    int i = rb >> 6, obase = rb & 63;

    for (int idx4 = t; idx4 < 4096; idx4 += 256) {
        int g = idx4 >> 4, c = (idx4 & 15) * 4;
        *(float4*)&lastL[g*65 + c] =
            *(const float4*)&h[((long)g*128 + 127)*64 + c];
    }
    {   // stage W5 slice, transposed to [j][rr]
        int rr = t & 15, j0 = (t >> 4) * 4;
        float4 w = *(const float4*)&W5[(long)(obase + rr)*4096 + i*64 + j0];
        wL[(j0+0)*16 + rr] = w.x;
        wL[(j0+1)*16 + rr] = w.y;
        wL[(j0+2)*16 + rr] = w.z;
        wL[(j0+3)*16 + rr] = w.w;
    }
    __syncthreads();

    int g = t;
    float acc[16] = {};
    for (int j = 0; j < 64; ++j) {
        float lv = lastL[g*65 + j];
        #pragma unroll
        for (int r4 = 0; r4 < 4; ++r4) {
            float4 wv = *(float4*)&wL[j*16 + r4*4];
            acc[r4*4+0] += wv.x * lv;
            acc[r4*4+1] += wv.y * lv;
            acc[r4*4+2] += wv.z * lv;
            acc[r4*4+3] += wv.w * lv;
        }
    }
    #pragma unroll
    for (int rr = 0; rr < 16; ++rr) tr[rr*257 + g] = acc[rr];
    __syncthreads();
    for (int it = 0; it < 4; ++it) {
        int idx = t + it*256;
        int g2 = idx >> 2, c4 = idx & 3;
        float4 v = make_float4(tr[(c4*4+0)*257 + g2], tr[(c4*4+1)*257 + g2],
                               tr[(c4*4+2)*257 + g2], tr[(c4*4+3)*257 + g2]);
        *(float4*)&Tt[(long)g2*4096 + rb + c4*4] = v;
    }
}

// ---------------------------------------------------------------------------
// k_readout: ONE block per graph (256 blocks), 4 p-tiles of 32.
// T and Wd1t staged once per graph (was twice).
// ---------------------------------------------------------------------------
__global__ void __launch_bounds__(256) k_readout(
        const float* __restrict__ h, const float* __restrict__ Tt,
        const float* __restrict__ b5, const float* __restrict__ Wd1t,
        const float* __restrict__ bd1, const float* __restrict__ Wd2,
        const float* __restrict__ bd2, float* __restrict__ out) {
    __shared__ float Tl[4096];       // [i][o], stride 64
    __shared__ float W1t[8192];      // [o][q], stride 128
    __shared__ float OY[32 * 68];    // [p][i] then [p][o], stride 68
    int t = threadIdx.x;
    int g = blockIdx.x;

    for (int i = t * 4; i < 4096; i += 1024)
        *(float4*)&Tl[i] = *(const float4*)&Tt[(long)g*4096 + i];
    for (int i = t * 4; i < 8192; i += 1024)
        *(float4*)&W1t[i] = *(const float4*)&Wd1t[i];

    int tc = t & 15, tr = t >> 4;      // GEMM1 map
    int o0 = tc * 4, p0 = tr * 2;
    int tc2 = t & 31, tr2 = t >> 5;    // GEMM2 map
    int q0 = tc2 * 4, pp0 = tr2 * 4;
    float4 b5_4  = *(const float4*)&b5[o0];
    float4 bd1_4 = *(const float4*)&bd1[q0];
    float4 wd2_4 = *(const float4*)&Wd2[q0];
    float bd2v = bd2[0];

    for (int pt = 0; pt < 4; ++pt) {
        int pbase = pt * 32;
        __syncthreads();  // previous tile's GEMM2 reads done; T/W1t staged
        for (int idx = t; idx < 512; idx += 256) {
            int p = idx >> 4, c = (idx & 15) * 4;
            *(float4*)&OY[p*68 + c] =
                *(const float4*)&h[((long)g*128 + pbase + p)*64 + c];
        }
        __syncthreads();

        // GEMM1
        float a10[4] = {0.f,0.f,0.f,0.f};
        float a11[4] = {0.f,0.f,0.f,0.f};
        #pragma unroll 4
        for (int i = 0; i < 64; i += 4) {
            float4 w0 = *(float4*)&Tl[(i+0)*64 + o0];
            float4 w1 = *(float4*)&Tl[(i+1)*64 + o0];
            float4 w2 = *(float4*)&Tl[(i+2)*64 + o0];
            float4 w3 = *(float4*)&Tl[(i+3)*64 + o0];
            float4 x0 = *(float4*)&OY[(p0+0)*68 + i];
            float4 x1 = *(float4*)&OY[(p0+1)*68 + i];
            a10[0] += x0.x*w0.x + x0.y*w1.x + x0.z*w2.x + x0.w*w3.x;
            a10[1] += x0.x*w0.y + x0.y*w1.y + x0.z*w2.y + x0.w*w3.y;
            a10[2] += x0.x*w0.z + x0.y*w1.z + x0.z*w2.z + x0.w*w3.z;
            a10[3] += x0.x*w0.w + x0.y*w1.w + x0.z*w2.w + x0.w*w3.w;
            a11[0] += x1.x*w0.x + x1.y*w1.x + x1.z*w2.x + x1.w*w3.x;
            a11[1] += x1.x*w0.y + x1.y*w1.y + x1.z*w2.y + x1.w*w3.y;
            a11[2] += x1.x*w0.z + x1.y*w1.z + x1.z*w2.z + x1.w*w3.z;
            a11[3] += x1.x*w0.w + x1.y*w1.w + x1.z*w2.w + x1.w*w3.w;
        }
        __syncthreads();  // all reads of O done; OY becomes Y

        float4 y0 = make_float4(a10[0]+b5_4.x, a10[1]+b5_4.y, a10[2]+b5_4.z, a10[3]+b5_4.w);
        float4 y1 = make_float4(a11[0]+b5_4.x, a11[1]+b5_4.y, a11[2]+b5_4.z, a11[3]+b5_4.w);
        *(float4*)&OY[(p0+0)*68 + o0] = y0;
        *(float4*)&OY[(p0+1)*68 + o0] = y1;
        __syncthreads();

        // GEMM2
        float a2[4][4] = {};
        #pragma unroll 4
        for (int o = 0; o < 64; o += 4) {
            float4 w0 = *(float4*)&W1t[(o+0)*128 + q0];
            float4 w1 = *(float4*)&W1t[(o+1)*128 + q0];
            float4 w2 = *(float4*)&W1t[(o+2)*128 + q0];
            float4 w3 = *(float4*)&W1t[(o+3)*128 + q0];
            #pragma unroll
            for (int jp = 0; jp < 4; ++jp) {
                float4 yv = *(float4*)&OY[(pp0+jp)*68 + o];
                a2[jp][0] += yv.x*w0.x + yv.y*w1.x + yv.z*w2.x + yv.w*w3.x;
                a2[jp][1] += yv.x*w0.y + yv.y*w1.y + yv.z*w2.y + yv.w*w3.y;
                a2[jp][2] += yv.x*w0.z + yv.y*w1.z + yv.z*w2.z + yv.w*w3.z;
                a2[jp][3] += yv.x*w0.w + yv.y*w1.w + yv.z*w2.w + yv.w*w3.w;
            }
        }

        #pragma unroll
        for (int jp = 0; jp < 4; ++jp) {
            float s = wd2_4.x * fmaxf(a2[jp][0] + bd1_4.x, 0.f)
                    + wd2_4.y * fmaxf(a2[jp][1] + bd1_4.y, 0.f)
                    + wd2_4.z * fmaxf(a2[jp][2] + bd1_4.z, 0.f)
                    + wd2_4.w * fmaxf(a2[jp][3] + bd1_4.w, 0.f);
            s += __shfl_xor(s, 1, 64);
            s += __shfl_xor(s, 2, 64);
            s += __shfl_xor(s, 4, 64);
            s += __shfl_xor(s, 8, 64);
            s += __shfl_xor(s, 16, 64);
            if (tc2 == 0) {
                int p = pbase + pp0 + jp;
                if (p < 127) out[g*127 + p] = s + bd2v;
            }
        }
    }
}

extern "C" void kernel_launch(void* const* d_in, const int* in_sizes, int n_in,
                              void* d_out, int out_size, void* d_ws, size_t ws_size,
                              hipStream_t stream) {
    const float* x   = (const float*)d_in[0];
    const int*   ei  = (const int*)d_in[1];   // [2][E] int32
    const float* W1  = (const float*)d_in[4];
    const float* b1  = (const float*)d_in[5];
    const float* W2  = (const float*)d_in[6];
    const float* b2  = (const float*)d_in[7];
    const float* W3  = (const float*)d_in[8];
    const float* b3  = (const float*)d_in[9];
    const float* W4  = (const float*)d_in[10];
    const float* b4  = (const float*)d_in[11];
    const float* W5  = (const float*)d_in[12];
    const float* b5  = (const float*)d_in[13];
    const float* Wd1 = (const float*)d_in[14];
    const float* bd1 = (const float*)d_in[15];
    const float* Wd2 = (const float*)d_in[16];
    const float* bd2 = (const float*)d_in[17];
    float* out = (float*)d_out;

    float* ws  = (float*)d_ws;
    float* h0   = ws;                        // (NN+1)*64 floats (row NN = zeros)
    float* h1   = ws + 2129984;              // (NN+1)*64 floats, 16-aligned
    float* Tt   = ws + 4259968;              // 2^20 floats
    float* Wc   = ws + 5308416;              // 8448 floats
    float* Wd1t = ws + 5316864;              // 8192 floats
    int*   deg  = (int*)(ws + 5325056);      // NN
    int*   csr  = deg + NN;                  // NN*64 ints (bucket CSR)

    const int* src = ei;
    const int* dst = ei + EE;

    k_init<<<8226, 256, 0, stream>>>(x, W1, b1, W2, b2, W3, b3, W4, b4,
                                     Wd1, h0, h1, Wc, Wd1t, deg, csr);
    k_fill<<<512, 256, 0, stream>>>(src, dst, deg, csr);

    float* hc = h0; float* hn = h1;
    for (int l = 0; l < 3; ++l) {
        // gather writes messages into hn rows 0..NN-1; k_gemm consumes them
        // in-place and overwrites hn with updated features (block-local
        // alias). Sentinel row NN of both buffers stays zero throughout.
        k_gather<<<NN/4, 256, 0, stream>>>(hc, deg, csr, hn);
        k_gemm<<<NN/64, 256, 0, stream>>>(Wc, hn, hc);
        float* tmp = hc; hc = hn; hn = tmp;
    }

    k_tmat<<<256, 256, 0, stream>>>(hc, W5, Tt);
    k_readout<<<256, 256, 0, stream>>>(hc, Tt, b5, Wd1t, bd1, Wd2, bd2, out);
}